// Round 1
// baseline (220.566 us; speedup 1.0000x reference)
//
#include <hip/hip_runtime.h>
#include <hip/hip_bf16.h>
#include <math.h>

// Problem constants
#define PB 8      // batch
#define PV 8      // vehicles
#define PN 1000   // nodes
#define PD 256    // dim
#define PH 8      // heads
#define PKS 32    // key size
#define BV 64     // B*V

// ws layout (float offsets)
#define OFF_MW      0          // 768*8      = 6144
#define OFF_QUERY   6144       // 64*256     = 16384
#define OFF_LOGMASK 22528      // 64000
#define OFF_CONC    86528      // 64*256     = 16384
#define OFF_FQ      102912     // 64*256     = 16384
#define OFF_LQM     119296     // 64*8       = 512
#define OFF_LOGITS  119808     // 64000
// total 183808 floats = ~735 KB

__device__ inline float waveMax(float v){
  #pragma unroll
  for (int o = 32; o > 0; o >>= 1) v = fmaxf(v, __shfl_down(v, o, 64));
  return v;
}
__device__ inline float waveSum(float v){
  #pragma unroll
  for (int o = 32; o > 0; o >>= 1) v += __shfl_down(v, o, 64);
  return v;
}

// K1: block types: [0,24) Mw rows; [24,88) query per (b,v); [88,338) logmask
__global__ __launch_bounds__(256) void k1_prep(
    const float* __restrict__ pns1, const float* __restrict__ pns2,
    const float* __restrict__ prev, const float* __restrict__ veh,
    const float* __restrict__ fixedc, const float* __restrict__ pcs,
    const void* __restrict__ maskp,
    float* __restrict__ mw, float* __restrict__ query, float* __restrict__ logmask)
{
  int blk = blockIdx.x, tid = threadIdx.x;
  if (blk < 24) {
    // Mw[i][f] = W1[i,f] + sum_j W2a[i,j]*W1[j,f]; Mw[i][7] = pns2[i*769+768]
    int g = blk * 256 + tid;      // g < 6144
    int i = g >> 3, f = g & 7;
    if (f == 7) {
      mw[g] = pns2[(size_t)i * 769 + 768];
    } else {
      float a = pns1[i * 7 + f];
      const float* row = pns2 + (size_t)i * 769;
      for (int j = 0; j < 768; j++) a += row[j] * pns1[j * 7 + f];
      mw[g] = a;
    }
  } else if (blk < 88) {
    // query[b,v,d] = fixed[b,d] + sum_k cvs[k]*pcs[d,k]
    int bv = blk - 24;
    __shared__ __align__(16) float cvs[264];
    if (tid < 256) cvs[tid] = prev[(size_t)bv * 256 + tid];
    if (tid < 8)   cvs[256 + tid] = veh[bv * 8 + tid];
    __syncthreads();
    int b = bv >> 3;
    float a = fixedc[b * 256 + tid];
    const float4* c4 = (const float4*)cvs;
    const float4* w4 = (const float4*)(pcs + (size_t)tid * 264);
    #pragma unroll 4
    for (int k = 0; k < 66; k++) {
      float4 cv = c4[k], wv = w4[k];
      a += cv.x*wv.x + cv.y*wv.y + cv.z*wv.z + cv.w*wv.w;
    }
    query[(size_t)bv * 256 + tid] = a;
  } else {
    // logmask with mask dtype auto-detect (bool-u8 vs int32)
    int g = (blk - 88) * 256 + tid;
    __shared__ int bytemode;
    if (tid == 0) {
      int bm = 0;
      const unsigned char* mb = (const unsigned char*)maskp;
      for (int idx = 1; idx < 256; idx++)
        if ((idx & 3) != 0 && mb[idx] != 0) { bm = 1; break; }
      bytemode = bm;
    }
    __syncthreads();
    if (g < 64000) {
      bool on = bytemode ? (((const unsigned char*)maskp)[g] != 0)
                         : (((const int*)maskp)[g] != 0);
      logmask[g] = on ? 0.0f : -INFINITY;
    }
  }
}

// K2: one block per (h,b). compat -> joint softmax over (v,n) -> heads
__global__ __launch_bounds__(1024) void k2_attn(
    const float* __restrict__ node_dyn, const float* __restrict__ gVs,
    const float* __restrict__ gKs, const float* __restrict__ mw,
    const float* __restrict__ query, const float* __restrict__ logmask,
    float* __restrict__ conc)
{
  int blk = blockIdx.x;
  int h = blk >> 3, b = blk & 7;   // blockIdx%8 = b -> same-b blocks share XCD L2
  int tid = threadIdx.x;

  __shared__ __align__(16) float p[8192];        // compat -> unnormalized probs
  __shared__ __align__(16) float part[16 * 256]; // reduction scratch
  __shared__ __align__(16) float gq[256];        // gQ[v][k]
  __shared__ float qmk[64];                      // qMk[v][f]
  __shared__ float mwv[256];                     // Mw V-part rows h*32+k
  __shared__ float hstat[256];                   // heads static [v][k]
  __shared__ float s8v[64];                      // s8[v][f]
  __shared__ float red[16];
  __shared__ float bstat[2];

  // phase 0: stage gQ and Mw slices
  if (tid < 256) {
    int v = tid >> 5, k = tid & 31;
    gq[tid] = query[(size_t)(b * 8 + v) * 256 + h * 32 + k];
  } else if (tid < 512) {
    int i2 = tid - 256; int k = i2 >> 3, f = i2 & 7;
    mwv[i2] = mw[(h * 32 + k) * 8 + f];
  }
  __syncthreads();
  if (tid < 64) {
    int v = tid >> 3, f = tid & 7;
    float a = 0.f;
    for (int k = 0; k < 32; k++)
      a += gq[v * 32 + k] * mw[(256 + h * 32 + k) * 8 + f];
    qmk[tid] = a;
  }
  __syncthreads();

  // phase 1: compat
  float tmax = -INFINITY;
  for (int e = tid; e < 8000; e += 1024) {
    int v = e / 1000; int n = e - v * 1000;
    const float4* nd4 = (const float4*)(node_dyn + ((size_t)(b * 8 + v) * 1000 + n) * 8);
    float4 ndA = nd4[0], ndB = nd4[1];
    const float4* gk4 = (const float4*)(gKs + ((size_t)(h * 8 + b) * 1000 + n) * 32);
    const float4* gq4 = (const float4*)(gq + v * 32);
    float s = 0.f;
    #pragma unroll
    for (int k4 = 0; k4 < 8; k4++) {
      float4 g = gk4[k4], q = gq4[k4];
      s += g.x*q.x + g.y*q.y + g.z*q.z + g.w*q.w;
    }
    const float* qm = qmk + v * 8;
    float dyn = ndA.x*qm[0] + ndA.y*qm[1] + ndA.z*qm[2] + ndA.w*qm[3]
              + ndB.x*qm[4] + ndB.y*qm[5] + ndB.z*qm[6] + ndB.w*qm[7];
    float c = (s + dyn) * 0.17677669529663687f + logmask[(b * 8 + v) * 1000 + n];
    p[e] = c;
    tmax = fmaxf(tmax, c);
  }
  tmax = waveMax(tmax);
  if ((tid & 63) == 0) red[tid >> 6] = tmax;
  __syncthreads();
  if (tid == 0) {
    float m = -INFINITY;
    for (int i = 0; i < 16; i++) m = fmaxf(m, red[i]);
    bstat[0] = m;
  }
  __syncthreads();
  float bmax = bstat[0];

  // phase 2: exp + sum
  float tsum = 0.f;
  for (int e = tid; e < 8000; e += 1024) {
    float pv = __expf(p[e] - bmax);
    p[e] = pv;
    tsum += pv;
  }
  tsum = waveSum(tsum);
  if ((tid & 63) == 0) red[tid >> 6] = tsum;
  __syncthreads();
  if (tid == 0) {
    float s = 0.f;
    for (int i = 0; i < 16; i++) s += red[i];
    bstat[1] = s;
  }
  __syncthreads();
  float linv = 1.0f / bstat[1];

  // phase 3: heads static = sum_n p * gVs
  {
    int s = tid >> 6, lane = tid & 63;
    int v = lane >> 3, k4 = lane & 7;
    float4 acc = {0.f, 0.f, 0.f, 0.f};
    const float* gv = gVs + ((size_t)(h * 8 + b) * 1000) * 32;
    for (int n = s; n < 1000; n += 16) {
      float pv = p[v * 1000 + n];
      float4 g = *(const float4*)(gv + n * 32 + k4 * 4);
      acc.x += pv * g.x; acc.y += pv * g.y; acc.z += pv * g.z; acc.w += pv * g.w;
    }
    *(float4*)(part + s * 256 + v * 32 + k4 * 4) = acc;
  }
  __syncthreads();
  if (tid < 256) {
    float a = 0.f;
    for (int s = 0; s < 16; s++) a += part[s * 256 + tid];
    hstat[tid] = a;
  }
  __syncthreads();

  // phase 4: s8[v][f] = sum_n p * nd8
  {
    int s = tid >> 6, lane = tid & 63;
    int v = lane >> 3, f = lane & 7;
    float a = 0.f;
    const float* nd = node_dyn + ((size_t)(b * 8 + v) * 1000) * 8 + f;
    for (int n = s; n < 1000; n += 16) a += p[v * 1000 + n] * nd[n * 8];
    part[s * 64 + lane] = a;
  }
  __syncthreads();
  if (tid < 64) {
    float a = 0.f;
    for (int s = 0; s < 16; s++) a += part[s * 64 + tid];
    s8v[tid] = a;
  }
  __syncthreads();

  // phase 5: heads = (static + dyn)/l  -> conc[b][v][h*32+k]
  if (tid < 256) {
    int v = tid >> 5, k = tid & 31;
    float dyn = 0.f;
    #pragma unroll
    for (int f = 0; f < 8; f++) dyn += s8v[v * 8 + f] * mwv[k * 8 + f];
    conc[(size_t)(b * 8 + v) * 256 + h * 32 + k] = (hstat[tid] + dyn) * linv;
  }
}

// K3: final_Q per (b,v) + lqM = Mw_L^T . fQ
__global__ __launch_bounds__(256) void k3_fq(
    const float* __restrict__ conc, const float* __restrict__ po,
    const float* __restrict__ mw, float* __restrict__ fq, float* __restrict__ lqm)
{
  int bv = blockIdx.x, tid = threadIdx.x;
  __shared__ __align__(16) float cl[256];
  __shared__ float fql[256];
  __shared__ float part[256];
  cl[tid] = conc[(size_t)bv * 256 + tid];
  __syncthreads();
  float a = 0.f;
  const float4* c4 = (const float4*)cl;
  const float4* w4 = (const float4*)(po + (size_t)tid * 256);
  #pragma unroll 4
  for (int e = 0; e < 64; e++) {
    float4 cv = c4[e], wv = w4[e];
    a += cv.x*wv.x + cv.y*wv.y + cv.z*wv.z + cv.w*wv.w;
  }
  fql[tid] = a;
  fq[(size_t)bv * 256 + tid] = a;
  __syncthreads();
  {
    int c = tid >> 3, f = tid & 7;
    float s = 0.f;
    for (int d = c * 8; d < c * 8 + 8; d++) s += fql[d] * mw[(512 + d) * 8 + f];
    part[tid] = s;
  }
  __syncthreads();
  if (tid < 8) {
    float s = 0.f;
    for (int c = 0; c < 32; c++) s += part[c * 8 + tid];
    lqm[bv * 8 + tid] = s;
  }
}

// K4a: logits[b,v,n] = tanh((fQ.(lKs+lKd))/16)*10 + logmask
__global__ __launch_bounds__(256) void k4a_logits(
    const float* __restrict__ lKs, const float* __restrict__ node_dyn,
    const float* __restrict__ fq, const float* __restrict__ lqm,
    const float* __restrict__ logmask, float* __restrict__ logits)
{
  int blk = blockIdx.x;
  int b = blk & 7, chunk = blk >> 3;
  int n0 = chunk * 32;
  int tid = threadIdx.x;
  __shared__ __align__(16) float lk[32 * 260];
  __shared__ __align__(16) float fql[8 * 260];
  __shared__ float lql[64];

  for (int idx = tid; idx < 2048; idx += 256) {
    int nn = idx >> 6, d4 = idx & 63;
    int n = n0 + nn;
    float4 v;
    if (n < 1000) v = *(const float4*)(lKs + ((size_t)b * 1000 + n) * 256 + d4 * 4);
    else { v.x = v.y = v.z = v.w = 0.f; }
    *(float4*)(lk + nn * 260 + d4 * 4) = v;
  }
  for (int idx = tid; idx < 512; idx += 256) {
    int v8 = idx >> 6, d4 = idx & 63;
    *(float4*)(fql + v8 * 260 + d4 * 4) =
        *(const float4*)(fq + (size_t)(b * 8 + v8) * 256 + d4 * 4);
  }
  if (tid < 64) lql[tid] = lqm[b * 64 + tid];
  __syncthreads();

  int v = tid & 7, nn = tid >> 3;
  int n = n0 + nn;
  if (n < 1000) {
    const float4* A  = (const float4*)(fql + v * 260);
    const float4* Bk = (const float4*)(lk + nn * 260);
    float s = 0.f;
    #pragma unroll 4
    for (int d4 = 0; d4 < 64; d4++) {
      float4 x = A[d4], y = Bk[d4];
      s += x.x*y.x + x.y*y.y + x.z*y.z + x.w*y.w;
    }
    const float4* nd4 = (const float4*)(node_dyn + ((size_t)(b * 8 + v) * 1000 + n) * 8);
    float4 na = nd4[0], nb = nd4[1];
    const float* q = lql + v * 8;
    float dyn = na.x*q[0] + na.y*q[1] + na.z*q[2] + na.w*q[3]
              + nb.x*q[4] + nb.y*q[5] + nb.z*q[6] + nb.w*q[7];
    float z = (s + dyn) * 0.0625f;
    logits[(size_t)(b * 8 + v) * 1000 + n] = tanhf(z) * 10.0f + logmask[(b * 8 + v) * 1000 + n];
  }
}

// K4b: per-b softmax over v*n, argmax, logprob, entropy
__global__ __launch_bounds__(1024) void k4b_out(
    const float* __restrict__ logits, float* __restrict__ out)
{
  int b = blockIdx.x, tid = threadIdx.x;
  __shared__ float rv[16]; __shared__ int ri[16];
  __shared__ float rs[16];
  __shared__ float bmaxs; __shared__ int bidxs;
  const float* L = logits + (size_t)b * 8000;

  float best = -INFINITY; int bi = 0;
  for (int e = tid; e < 8000; e += 1024) {
    float v = L[e];
    if (v > best) { best = v; bi = e; }   // increasing e -> keeps first on ties
  }
  #pragma unroll
  for (int o = 32; o > 0; o >>= 1) {
    float ov = __shfl_down(best, o, 64);
    int   oi = __shfl_down(bi, o, 64);
    if (ov > best || (ov == best && oi < bi)) { best = ov; bi = oi; }
  }
  if ((tid & 63) == 0) { rv[tid >> 6] = best; ri[tid >> 6] = bi; }
  __syncthreads();
  if (tid == 0) {
    float m = -INFINITY; int mi = 0;
    for (int i = 0; i < 16; i++)
      if (rv[i] > m || (rv[i] == m && ri[i] < mi)) { m = rv[i]; mi = ri[i]; }
    bmaxs = m; bidxs = mi;
  }
  __syncthreads();
  float m = bmaxs;
  float s = 0.f;
  for (int e = tid; e < 8000; e += 1024) s += __expf(L[e] - m);
  s = waveSum(s);
  if ((tid & 63) == 0) rs[tid >> 6] = s;
  __syncthreads();
  if (tid == 0) {
    float S = 0.f;
    for (int i = 0; i < 16; i++) S += rs[i];
    float lse = logf(S);
    float prob = 1.0f / S;
    int op = bidxs;
    out[b]      = (float)(op / 1000);
    out[8 + b]  = (float)(op % 1000);
    out[16 + b] = -lse;
    atomicAdd(out + 24, prob * lse);   // sums to entropy across b
  }
}

extern "C" void kernel_launch(void* const* d_in, const int* in_sizes, int n_in,
                              void* d_out, int out_size, void* d_ws, size_t ws_size,
                              hipStream_t stream) {
  const float* fixedc   = (const float*)d_in[1];
  const float* prev     = (const float*)d_in[2];
  const float* node_dyn = (const float*)d_in[3];
  const float* veh      = (const float*)d_in[4];
  const float* gVs      = (const float*)d_in[5];
  const float* gKs      = (const float*)d_in[6];
  const float* lKs      = (const float*)d_in[7];
  const void*  mask     = d_in[8];
  const float* pcs      = (const float*)d_in[9];
  const float* pns1     = (const float*)d_in[10];
  const float* pns2     = (const float*)d_in[11];
  const float* po       = (const float*)d_in[12];
  float* W   = (float*)d_ws;
  float* out = (float*)d_out;

  hipMemsetAsync(d_out, 0, 25 * sizeof(float), stream);
  k1_prep<<<338, 256, 0, stream>>>(pns1, pns2, prev, veh, fixedc, pcs, mask,
                                   W + OFF_MW, W + OFF_QUERY, W + OFF_LOGMASK);
  k2_attn<<<64, 1024, 0, stream>>>(node_dyn, gVs, gKs, W + OFF_MW, W + OFF_QUERY,
                                   W + OFF_LOGMASK, W + OFF_CONC);
  k3_fq<<<64, 256, 0, stream>>>(W + OFF_CONC, po, W + OFF_MW, W + OFF_FQ, W + OFF_LQM);
  k4a_logits<<<256, 256, 0, stream>>>(lKs, node_dyn, W + OFF_FQ, W + OFF_LQM,
                                      W + OFF_LOGMASK, W + OFF_LOGITS);
  k4b_out<<<8, 1024, 0, stream>>>(W + OFF_LOGITS, out);
}

// Round 2
// 191.649 us; speedup vs baseline: 1.1509x; 1.1509x over previous
//
#include <hip/hip_runtime.h>
#include <hip/hip_bf16.h>
#include <math.h>

// Problem constants: B=8, V=8, N=1000, D=256, H=8, KS=32
// ws layout (float offsets)
#define OFF_MW      0          // 768*8   = 6144
#define OFF_QUERY   6144       // 64*256  = 16384 -> 22528
#define OFF_LOGMASK 22528      // 64000           -> 86528
#define OFF_COMPAT  86528      // 64*8000 = 512000-> 598528
#define OFF_CMAX    598528     // 64 (monotone-encoded uint)
#define OFF_CSUM    598592     // 64
#define OFF_HSTAT   598656     // 64*256  = 16384 -> 615040
#define OFF_S8      615040     // 64*64   = 4096  -> 619136
#define OFF_FQ      619136     // 64*256  = 16384 -> 635520
#define OFF_LQM     635520     // 64*8    = 512   -> 636032
#define OFF_LOGITS  636032     // 64000           -> 700032 floats (~2.8 MB)
// stats region to memset each launch: [OFF_CMAX, OFF_S8 end) = 20608 floats

__device__ inline float waveMax(float v){
  #pragma unroll
  for (int o = 32; o > 0; o >>= 1) v = fmaxf(v, __shfl_down(v, o, 64));
  return v;
}
__device__ inline float waveSum(float v){
  #pragma unroll
  for (int o = 32; o > 0; o >>= 1) v += __shfl_down(v, o, 64);
  return v;
}
// monotone float<->uint encoding for atomicMax over floats (handles -inf)
__device__ inline unsigned encF(float f){
  unsigned u = __float_as_uint(f);
  return (u & 0x80000000u) ? ~u : (u | 0x80000000u);
}
__device__ inline float decF(unsigned u){
  return (u & 0x80000000u) ? __uint_as_float(u & 0x7fffffffu)
                           : __uint_as_float(~u);
}

// K1: [0,768) Mw rows (one row per block); [768,832) query per (b,v);
//     [832,1082) logmask
__global__ __launch_bounds__(256) void k1_prep(
    const float* __restrict__ pns1, const float* __restrict__ pns2,
    const float* __restrict__ prev, const float* __restrict__ veh,
    const float* __restrict__ fixedc, const float* __restrict__ pcs,
    const void* __restrict__ maskp,
    float* __restrict__ mw, float* __restrict__ query, float* __restrict__ logmask)
{
  int blk = blockIdx.x, tid = threadIdx.x;
  if (blk < 768) {
    // Mw[i][f] = W1[i,f] + sum_j W2a[i,j]*W1[j,f]; Mw[i][7] = pns2[i*769+768]
    int i = blk;
    __shared__ float red[4 * 7];
    const float* row = pns2 + (size_t)i * 769;
    float acc[7] = {0.f,0.f,0.f,0.f,0.f,0.f,0.f};
    #pragma unroll
    for (int t = 0; t < 3; t++) {
      int j = tid + 256 * t;
      float r = row[j];
      const float* w = pns1 + j * 7;
      #pragma unroll
      for (int f = 0; f < 7; f++) acc[f] += r * w[f];
    }
    #pragma unroll
    for (int f = 0; f < 7; f++) {
      float v = waveSum(acc[f]);
      if ((tid & 63) == 0) red[(tid >> 6) * 7 + f] = v;
    }
    __syncthreads();
    if (tid < 7) {
      float s = red[tid] + red[7 + tid] + red[14 + tid] + red[21 + tid];
      mw[i * 8 + tid] = pns1[i * 7 + tid] + s;
    } else if (tid == 7) {
      mw[i * 8 + 7] = row[768];
    }
  } else if (blk < 832) {
    // query[b,v,d] = fixed[b,d] + sum_k cvs[k]*pcs[d,k]
    int bv = blk - 768;
    __shared__ __align__(16) float cvs[264];
    if (tid < 256) cvs[tid] = prev[(size_t)bv * 256 + tid];
    if (tid < 8)   cvs[256 + tid] = veh[bv * 8 + tid];
    __syncthreads();
    int b = bv >> 3;
    float a = fixedc[b * 256 + tid];
    const float4* c4 = (const float4*)cvs;
    const float4* w4 = (const float4*)(pcs + (size_t)tid * 264);
    #pragma unroll 4
    for (int k = 0; k < 66; k++) {
      float4 cv = c4[k], wv = w4[k];
      a += cv.x*wv.x + cv.y*wv.y + cv.z*wv.z + cv.w*wv.w;
    }
    query[(size_t)bv * 256 + tid] = a;
  } else {
    // logmask with mask dtype auto-detect (bool-u8 vs int32)
    int g = (blk - 832) * 256 + tid;
    __shared__ int bytemode;
    if (tid == 0) {
      int bm = 0;
      const unsigned char* mb = (const unsigned char*)maskp;
      for (int idx = 1; idx < 256; idx++)
        if ((idx & 3) != 0 && mb[idx] != 0) { bm = 1; break; }
      bytemode = bm;
    }
    __syncthreads();
    if (g < 64000) {
      bool on = bytemode ? (((const unsigned char*)maskp)[g] != 0)
                         : (((const int*)maskp)[g] != 0);
      logmask[g] = on ? 0.0f : -INFINITY;
    }
  }
}

// K2a: grid 512 = (h, c, b). compat for 125 nodes x 8 v; atomicMax block max.
__global__ __launch_bounds__(256) void k2a_compat(
    const float* __restrict__ node_dyn, const float* __restrict__ gKs,
    const float* __restrict__ mw, const float* __restrict__ query,
    const float* __restrict__ logmask,
    float* __restrict__ compat, unsigned* __restrict__ cmax)
{
  int blk = blockIdx.x;
  int b = blk & 7, c = (blk >> 3) & 7, h = blk >> 6;
  int hb = h * 8 + b;
  int n0 = c * 125;
  int tid = threadIdx.x;
  __shared__ __align__(16) float gq[256];
  __shared__ float qmk[64];
  __shared__ float redm[4];

  gq[tid] = query[(size_t)(b * 8 + (tid >> 5)) * 256 + h * 32 + (tid & 31)];
  __syncthreads();
  if (tid < 64) {
    int v = tid >> 3, f = tid & 7;
    float a = 0.f;
    for (int k = 0; k < 32; k++)
      a += gq[v * 32 + k] * mw[(256 + h * 32 + k) * 8 + f];
    qmk[tid] = a;
  }
  __syncthreads();

  float tmax = -INFINITY;
  for (int e = tid; e < 1000; e += 256) {
    int v = e / 125;
    int n = n0 + (e - v * 125);
    const float4* nd4 = (const float4*)(node_dyn + ((size_t)(b * 8 + v) * 1000 + n) * 8);
    float4 ndA = nd4[0], ndB = nd4[1];
    const float4* gk4 = (const float4*)(gKs + ((size_t)hb * 1000 + n) * 32);
    const float4* gq4 = (const float4*)(gq + v * 32);
    float s = 0.f;
    #pragma unroll
    for (int k4 = 0; k4 < 8; k4++) {
      float4 g = gk4[k4], q = gq4[k4];
      s += g.x*q.x + g.y*q.y + g.z*q.z + g.w*q.w;
    }
    const float* qm = qmk + v * 8;
    float dyn = ndA.x*qm[0] + ndA.y*qm[1] + ndA.z*qm[2] + ndA.w*qm[3]
              + ndB.x*qm[4] + ndB.y*qm[5] + ndB.z*qm[6] + ndB.w*qm[7];
    float cc = (s + dyn) * 0.17677669529663687f + logmask[(b * 8 + v) * 1000 + n];
    compat[(size_t)hb * 8000 + v * 1000 + n] = cc;
    tmax = fmaxf(tmax, cc);
  }
  tmax = waveMax(tmax);
  if ((tid & 63) == 0) redm[tid >> 6] = tmax;
  __syncthreads();
  if (tid == 0) {
    float m = fmaxf(fmaxf(redm[0], redm[1]), fmaxf(redm[2], redm[3]));
    atomicMax(cmax + hb, encF(m));
  }
}

// K2b: grid 512 (same mapping). exp + atomic accumulation of sum/heads/s8.
__global__ __launch_bounds__(256) void k2b_accum(
    const float* __restrict__ node_dyn, const float* __restrict__ gVs,
    const float* __restrict__ compat, const unsigned* __restrict__ cmax,
    float* __restrict__ csum, float* __restrict__ hstat, float* __restrict__ s8)
{
  int blk = blockIdx.x;
  int b = blk & 7, c = (blk >> 3) & 7, h = blk >> 6;
  int hb = h * 8 + b;
  int n0 = c * 125;
  int tid = threadIdx.x;
  __shared__ float pl[1000];   // [v][125]
  __shared__ float reds[4];

  float bmax = decF(cmax[hb]);
  float tsum = 0.f;
  for (int e = tid; e < 1000; e += 256) {
    int v = e / 125;
    int i = e - v * 125;
    float p = __expf(compat[(size_t)hb * 8000 + v * 1000 + n0 + i] - bmax);
    pl[v * 125 + i] = p;
    tsum += p;
  }
  tsum = waveSum(tsum);
  if ((tid & 63) == 0) reds[tid >> 6] = tsum;
  __syncthreads();
  if (tid == 0) atomicAdd(csum + hb, reds[0] + reds[1] + reds[2] + reds[3]);

  // heads static partial: hstat[hb][v][k] += sum_i p * gVs
  {
    int v = tid >> 5, k = tid & 31;
    const float* gv = gVs + ((size_t)hb * 1000 + n0) * 32 + k;
    const float* pv = pl + v * 125;
    float a = 0.f;
    #pragma unroll 5
    for (int i = 0; i < 125; i++) a += pv[i] * gv[i * 32];
    atomicAdd(hstat + hb * 256 + tid, a);
  }
  // s8 partial: s8[hb][v][f] += sum_i p * nd8
  if (tid < 64) {
    int v = tid >> 3, f = tid & 7;
    const float* nd = node_dyn + ((size_t)(b * 8 + v) * 1000 + n0) * 8 + f;
    const float* pv = pl + v * 125;
    float a = 0.f;
    #pragma unroll 5
    for (int i = 0; i < 125; i++) a += pv[i] * nd[i * 8];
    atomicAdd(s8 + hb * 64 + tid, a);
  }
}

// K3: conc assembly (normalize) + final_Q per (b,v) + lqM
__global__ __launch_bounds__(256) void k3_fq(
    const float* __restrict__ hstat, const float* __restrict__ s8,
    const float* __restrict__ csum, const float* __restrict__ mw,
    const float* __restrict__ po, float* __restrict__ fq, float* __restrict__ lqm)
{
  int bv = blockIdx.x; int b = bv >> 3, v = bv & 7;
  int tid = threadIdx.x;
  __shared__ __align__(16) float cl[256];
  __shared__ float fql[256];
  __shared__ float part[256];
  {
    int h = tid >> 5, k = tid & 31, hb = h * 8 + b;
    float dyn = 0.f;
    const float* s8p = s8 + hb * 64 + v * 8;
    const float* mwp = mw + (h * 32 + k) * 8;
    #pragma unroll
    for (int f = 0; f < 8; f++) dyn += s8p[f] * mwp[f];
    cl[tid] = (hstat[hb * 256 + v * 32 + k] + dyn) / csum[hb];
  }
  __syncthreads();
  float a = 0.f;
  const float4* c4 = (const float4*)cl;
  const float4* w4 = (const float4*)(po + (size_t)tid * 256);
  #pragma unroll 4
  for (int e = 0; e < 64; e++) {
    float4 cv = c4[e], wv = w4[e];
    a += cv.x*wv.x + cv.y*wv.y + cv.z*wv.z + cv.w*wv.w;
  }
  fql[tid] = a;
  fq[(size_t)bv * 256 + tid] = a;
  __syncthreads();
  {
    int cc = tid >> 3, f = tid & 7;
    float s = 0.f;
    for (int d = cc * 8; d < cc * 8 + 8; d++) s += fql[d] * mw[(512 + d) * 8 + f];
    part[tid] = s;
  }
  __syncthreads();
  if (tid < 8) {
    float s = 0.f;
    for (int cc = 0; cc < 32; cc++) s += part[cc * 8 + tid];
    lqm[bv * 8 + tid] = s;
  }
}

// K4a: grid 1000 = (c,b); 4 threads cooperate per (v,n) dot over d=256.
__global__ __launch_bounds__(256) void k4a_logits(
    const float* __restrict__ lKs, const float* __restrict__ node_dyn,
    const float* __restrict__ fq, const float* __restrict__ lqm,
    const float* __restrict__ logmask, float* __restrict__ logits)
{
  int blk = blockIdx.x;
  int b = blk & 7, c = blk >> 3;       // c in [0,125)
  int n0 = c * 8;
  int tid = threadIdx.x;
  int q = tid & 3, v = (tid >> 2) & 7, nn = tid >> 5;
  int n = n0 + nn;
  const float4* A  = (const float4*)(fq + (size_t)(b * 8 + v) * 256 + q * 64);
  const float4* Bk = (const float4*)(lKs + ((size_t)b * 1000 + n) * 256 + q * 64);
  float s = 0.f;
  #pragma unroll
  for (int d4 = 0; d4 < 16; d4++) {
    float4 x = A[d4], y = Bk[d4];
    s += x.x*y.x + x.y*y.y + x.z*y.z + x.w*y.w;
  }
  s += __shfl_xor(s, 1, 64);
  s += __shfl_xor(s, 2, 64);
  if (q == 0) {
    const float4* nd4 = (const float4*)(node_dyn + ((size_t)(b * 8 + v) * 1000 + n) * 8);
    float4 na = nd4[0], nb = nd4[1];
    const float* qm = lqm + (b * 8 + v) * 8;
    float dyn = na.x*qm[0] + na.y*qm[1] + na.z*qm[2] + na.w*qm[3]
              + nb.x*qm[4] + nb.y*qm[5] + nb.z*qm[6] + nb.w*qm[7];
    float z = (s + dyn) * 0.0625f;
    logits[(size_t)(b * 8 + v) * 1000 + n] = tanhf(z) * 10.0f
                                           + logmask[(b * 8 + v) * 1000 + n];
  }
}

// K4b: per-b softmax over v*n, argmax, logprob, entropy
__global__ __launch_bounds__(1024) void k4b_out(
    const float* __restrict__ logits, float* __restrict__ out)
{
  int b = blockIdx.x, tid = threadIdx.x;
  __shared__ float rv[16]; __shared__ int ri[16];
  __shared__ float rs[16];
  __shared__ float bmaxs; __shared__ int bidxs;
  const float* L = logits + (size_t)b * 8000;

  float best = -INFINITY; int bi = 0;
  for (int e = tid; e < 8000; e += 1024) {
    float v = L[e];
    if (v > best) { best = v; bi = e; }
  }
  #pragma unroll
  for (int o = 32; o > 0; o >>= 1) {
    float ov = __shfl_down(best, o, 64);
    int   oi = __shfl_down(bi, o, 64);
    if (ov > best || (ov == best && oi < bi)) { best = ov; bi = oi; }
  }
  if ((tid & 63) == 0) { rv[tid >> 6] = best; ri[tid >> 6] = bi; }
  __syncthreads();
  if (tid == 0) {
    float m = -INFINITY; int mi = 0;
    for (int i = 0; i < 16; i++)
      if (rv[i] > m || (rv[i] == m && ri[i] < mi)) { m = rv[i]; mi = ri[i]; }
    bmaxs = m; bidxs = mi;
  }
  __syncthreads();
  float m = bmaxs;
  float s = 0.f;
  for (int e = tid; e < 8000; e += 1024) s += __expf(L[e] - m);
  s = waveSum(s);
  if ((tid & 63) == 0) rs[tid >> 6] = s;
  __syncthreads();
  if (tid == 0) {
    float S = 0.f;
    for (int i = 0; i < 16; i++) S += rs[i];
    float lse = logf(S);
    float prob = 1.0f / S;
    int op = bidxs;
    out[b]      = (float)(op / 1000);
    out[8 + b]  = (float)(op % 1000);
    out[16 + b] = -lse;
    atomicAdd(out + 24, prob * lse);
  }
}

extern "C" void kernel_launch(void* const* d_in, const int* in_sizes, int n_in,
                              void* d_out, int out_size, void* d_ws, size_t ws_size,
                              hipStream_t stream) {
  const float* fixedc   = (const float*)d_in[1];
  const float* prev     = (const float*)d_in[2];
  const float* node_dyn = (const float*)d_in[3];
  const float* veh      = (const float*)d_in[4];
  const float* gVs      = (const float*)d_in[5];
  const float* gKs      = (const float*)d_in[6];
  const float* lKs      = (const float*)d_in[7];
  const void*  mask     = d_in[8];
  const float* pcs      = (const float*)d_in[9];
  const float* pns1     = (const float*)d_in[10];
  const float* pns2     = (const float*)d_in[11];
  const float* po       = (const float*)d_in[12];
  float* W   = (float*)d_ws;
  float* out = (float*)d_out;

  hipMemsetAsync(d_out, 0, 25 * sizeof(float), stream);
  hipMemsetAsync(W + OFF_CMAX, 0, 20608 * sizeof(float), stream);  // cmax..s8

  k1_prep<<<1082, 256, 0, stream>>>(pns1, pns2, prev, veh, fixedc, pcs, mask,
                                    W + OFF_MW, W + OFF_QUERY, W + OFF_LOGMASK);
  k2a_compat<<<512, 256, 0, stream>>>(node_dyn, gKs, W + OFF_MW, W + OFF_QUERY,
                                      W + OFF_LOGMASK, W + OFF_COMPAT,
                                      (unsigned*)(W + OFF_CMAX));
  k2b_accum<<<512, 256, 0, stream>>>(node_dyn, gVs, W + OFF_COMPAT,
                                     (const unsigned*)(W + OFF_CMAX),
                                     W + OFF_CSUM, W + OFF_HSTAT, W + OFF_S8);
  k3_fq<<<64, 256, 0, stream>>>(W + OFF_HSTAT, W + OFF_S8, W + OFF_CSUM,
                                W + OFF_MW, po, W + OFF_FQ, W + OFF_LQM);
  k4a_logits<<<1000, 256, 0, stream>>>(lKs, node_dyn, W + OFF_FQ, W + OFF_LQM,
                                       W + OFF_LOGMASK, W + OFF_LOGITS);
  k4b_out<<<8, 1024, 0, stream>>>(W + OFF_LOGITS, out);
}